// Round 4
// baseline (340.151 us; speedup 1.0000x reference)
//
#include <hip/hip_runtime.h>

// CoarseMatching dual-softmax on MI355X — round 6.
// N=2, L=S=4800, C=256. sim = f0.f1^T/(256*0.1); conf = softmax_l * softmax_s.
// Diagnosis r0-r5: every pass writing ~190MB runs at ~1.5 TB/s write-drain;
// GEMM schedule is NOT the bound. => minimal-write structure (write conf ONCE):
//   pass 0: f16 hi/lo GEMM -> e in regs -> atomic rs/cs only (no big write)
//   pass 1: recompute e, conf = e^2*(1/rs)*(1/cs), nontemporal store, rcm=atomicMax
// Shared-B: B stored once (K=256), each B frag feeds 2 MFMAs (a_hi, a_lo):
//   -25% LDS traffic, -50% B fetch/convert, 48KB LDS -> 3 blocks/CU.

#define Ncst 2
#define Lc 4800
#define Sc 4800
#define Cc 256
#define KA 512          // A expanded K: [a_hi | a_lo]
#define KB 256          // B stored once: [b_hi]
#define LP 4864         // 4800 padded to 38*128
#define THRC 0.2f

typedef float f32x4 __attribute__((ext_vector_type(4)));
typedef _Float16 f16x8 __attribute__((ext_vector_type(8)));

#define AS1(p) ((__attribute__((address_space(1))) void*)(p))
#define AS3(p) ((__attribute__((address_space(3))) void*)(p))

// ---------------- conversion (+ zero accumulators) ---------------------------
// A2 [N][LP][512] = [a_hi | a_lo]; B2 [N][LP][256] = [b_hi]
__global__ __launch_bounds__(256) void convert_kernel(
    const float* __restrict__ f0, const float* __restrict__ f1,
    unsigned short* __restrict__ A2, unsigned short* __restrict__ B2,
    float* __restrict__ rs, float* __restrict__ cs, float* __restrict__ rcm)
{
    int idx = blockIdx.x * 256 + threadIdx.x;      // over N*LP*(C/8)
    if (idx < Ncst * Lc) { rs[idx] = 0.f; cs[idx] = 0.f; rcm[idx] = 0.f; }
    if (idx >= Ncst * LP * (Cc / 8)) return;
    int k8  = idx & (Cc / 8 - 1);                  // 0..31
    int row = (idx >> 5) % LP;
    int n   = idx / (LP * (Cc / 8));

    float av[8], bv[8];
    if (row < Lc) {
        const float4* pa = (const float4*)(f0 + ((size_t)n * Lc + row) * Cc + k8 * 8);
        float4 a0 = pa[0], a1 = pa[1];
        av[0]=a0.x; av[1]=a0.y; av[2]=a0.z; av[3]=a0.w;
        av[4]=a1.x; av[5]=a1.y; av[6]=a1.z; av[7]=a1.w;
        const float4* pb = (const float4*)(f1 + ((size_t)n * Sc + row) * Cc + k8 * 8);
        float4 b0 = pb[0], b1 = pb[1];
        bv[0]=b0.x; bv[1]=b0.y; bv[2]=b0.z; bv[3]=b0.w;
        bv[4]=b1.x; bv[5]=b1.y; bv[6]=b1.z; bv[7]=b1.w;
    } else {
        for (int i = 0; i < 8; ++i) { av[i] = 0.f; bv[i] = 0.f; }
    }

    _Float16 ahi[8], alo[8], bhi[8];
#pragma unroll
    for (int i = 0; i < 8; ++i) {
        _Float16 h = (_Float16)av[i];
        ahi[i] = h;
        alo[i] = (_Float16)(av[i] - (float)h);
        bhi[i] = (_Float16)bv[i];
    }
    size_t abase = ((size_t)n * LP + row) * KA + k8 * 8;
    size_t bbase = ((size_t)n * LP + row) * KB + k8 * 8;
    *(uint4*)&A2[abase]       = *(uint4*)ahi;
    *(uint4*)&A2[abase + 256] = *(uint4*)alo;
    *(uint4*)&B2[bbase]       = *(uint4*)bhi;
}

// ---------------- GEMM passes ------------------------------------------------
// 128x128 tile, 4 waves (2x2), wave-tile 64x64 = acc[4][4] via 16x16x32 f16.
// Real-K loop: 8 b-tiles of 32 k. Per tile per wave: 12 ds_read_b128
// (a_hi[4], a_lo[4], b[4]) and 32 MFMA (each b frag used twice).
// LDS: 2 bufs x 3 regions (Ahi, Alo, B) x 512 slots x 16B = 48 KB.
// Slot swizzle (proven r3, 0 conflicts): slot(row,q) = row*4 + (q ^ ((row>>1)&3)).
// Double-buffer: issue 6 gload_lds for tile t+1, read+MFMA tile t, syncthreads.
template <int PASS>
__global__ __launch_bounds__(256, 3) void gemm_kernel(
    const unsigned short* __restrict__ A2, const unsigned short* __restrict__ B2,
    float* __restrict__ out, float* __restrict__ rs, float* __restrict__ cs,
    int* __restrict__ rcm)
{
    __shared__ __attribute__((aligned(16))) unsigned short lds[2][1536 * 8]; // 48 KB

    // bijective XCD-aware swizzle: grid = 38*38*2 = 2888 = 8*361
    int flat = blockIdx.x + 38 * blockIdx.y + 1444 * blockIdx.z;
    int m    = (flat & 7) * 361 + (flat >> 3);
    const int tn = m % 38;
    const int tm = (m / 38) % 38;
    const int n  = m / 1444;

    const int tid  = threadIdx.x;
    const int wave = tid >> 6;
    const int lane = tid & 63;
    const int wm   = wave >> 1;     // 0..1
    const int wn   = wave & 1;      // 0..1
    const int ml   = lane & 15;
    const int kq   = lane >> 4;     // 0..3

    const unsigned short* Ab = A2 + ((size_t)n * LP + (size_t)tm * 128) * KA;
    const unsigned short* Bb = B2 + ((size_t)n * LP + (size_t)tn * 128) * KB;

    // staging: 6 chunks/thread = regions {Ahi,Alo,B} x halves {0,1}
    // region slot s (0..511): row = s>>2, q = (s&3)^((row>>1)&3)
    const unsigned short* gsrc[6];
    int gdst[6];
#pragma unroll
    for (int c = 0; c < 6; ++c) {
        int reg = c >> 1;                      // 0=Ahi 1=Alo 2=B
        int s   = (c & 1) * 256 + tid;         // slot in region
        int row = s >> 2;
        int q   = (s & 3) ^ ((row >> 1) & 3);
        if (reg == 0)      gsrc[c] = Ab + (size_t)row * KA + q * 8;
        else if (reg == 1) gsrc[c] = Ab + (size_t)row * KA + 256 + q * 8;
        else               gsrc[c] = Bb + (size_t)row * KB + q * 8;
        gdst[c] = (reg * 512 + s) * 8;
    }

    // fragment LDS element offsets (region-relative slot*8)
    int aoff[4], boff[4];
#pragma unroll
    for (int i = 0; i < 4; ++i) {
        int ar = wm * 64 + i * 16 + ml;
        aoff[i] = (ar * 4 + (kq ^ ((ar >> 1) & 3))) * 8;
        int br = wn * 64 + i * 16 + ml;
        boff[i] = (br * 4 + (kq ^ ((br >> 1) & 3))) * 8;
    }

#define STAGE(bb, tt) do { _Pragma("unroll") for (int c_ = 0; c_ < 6; ++c_) \
    __builtin_amdgcn_global_load_lds(AS1(gsrc[c_] + (tt) * 32), AS3(&lds[bb][gdst[c_]]), 16, 0, 0); } while (0)

    f32x4 acc[4][4] = {};

    STAGE(0, 0);
    __syncthreads();

#pragma unroll
    for (int t = 0; t < 8; ++t) {
        const int b = t & 1;
        if (t < 7) STAGE(b ^ 1, t + 1);
        f16x8 ah[4], al[4], bf_[4];
#pragma unroll
        for (int i = 0; i < 4; ++i) {
            ah[i]  = *(const f16x8*)&lds[b][aoff[i]];
            al[i]  = *(const f16x8*)&lds[b][4096 + aoff[i]];
            bf_[i] = *(const f16x8*)&lds[b][8192 + boff[i]];
        }
#pragma unroll
        for (int i = 0; i < 4; ++i)
#pragma unroll
            for (int j = 0; j < 4; ++j) {
                acc[i][j] = __builtin_amdgcn_mfma_f32_16x16x32_f16(ah[i], bf_[j], acc[i][j], 0, 0, 0);
                acc[i][j] = __builtin_amdgcn_mfma_f32_16x16x32_f16(al[i], bf_[j], acc[i][j], 0, 0, 0);
            }
        __syncthreads();   // drains vmcnt: tile t+1 loads landed during MFMAs
    }
#undef STAGE

    // D frag: col = ml, row = kq*4 + r
    const float alpha = 5.0f / 128.0f;          // 1/(256*0.1), exact in fp32

    if constexpr (PASS == 0) {
        // e in regs; accumulate row/col sums only
#pragma unroll
        for (int i = 0; i < 4; ++i)
#pragma unroll
            for (int r = 0; r < 4; ++r) {
                int gl = tm * 128 + wm * 64 + i * 16 + kq * 4 + r;
                bool rok = gl < Lc;
#pragma unroll
                for (int j = 0; j < 4; ++j) {
                    int gs = tn * 128 + wn * 64 + j * 16 + ml;
                    bool ok = rok && (gs < Sc);
                    acc[i][j][r] = ok ? __expf(acc[i][j][r] * alpha) : 0.f;
                }
            }
        // row sums: reduce over j and ml lanes (xor 1,2,4,8 stays in quarter)
#pragma unroll
        for (int i = 0; i < 4; ++i)
#pragma unroll
            for (int r = 0; r < 4; ++r) {
                float rp = acc[i][0][r] + acc[i][1][r] + acc[i][2][r] + acc[i][3][r];
                rp += __shfl_xor(rp, 1);
                rp += __shfl_xor(rp, 2);
                rp += __shfl_xor(rp, 4);
                rp += __shfl_xor(rp, 8);
                int gl = tm * 128 + wm * 64 + i * 16 + kq * 4 + r;
                if (ml == 0 && gl < Lc) atomicAdd(&rs[(size_t)n * Lc + gl], rp);
            }
        // col sums: reduce over i,r and kq (xor 16, 32)
#pragma unroll
        for (int j = 0; j < 4; ++j) {
            float cp = 0.f;
#pragma unroll
            for (int i = 0; i < 4; ++i)
#pragma unroll
                for (int r = 0; r < 4; ++r) cp += acc[i][j][r];
            cp += __shfl_xor(cp, 16);
            cp += __shfl_xor(cp, 32);
            int gs = tn * 128 + wn * 64 + j * 16 + ml;
            if (kq == 0 && gs < Sc) atomicAdd(&cs[(size_t)n * Sc + gs], cp);
        }
    } else {
        // conf = e^2*(1/rs)*(1/cs); nontemporal store; row-max via atomicMax
        float cin[4];
#pragma unroll
        for (int j = 0; j < 4; ++j) {
            int gs = tn * 128 + wn * 64 + j * 16 + ml;
            cin[j] = (gs < Sc) ? 1.0f / cs[(size_t)n * Sc + gs] : 0.f;
        }
#pragma unroll
        for (int i = 0; i < 4; ++i)
#pragma unroll
            for (int r = 0; r < 4; ++r) {
                int gl = tm * 128 + wm * 64 + i * 16 + kq * 4 + r;
                bool rok = gl < Lc;
                float ri = rok ? 1.0f / rs[(size_t)n * Lc + gl] : 0.f;
                float rmax = 0.f;
#pragma unroll
                for (int j = 0; j < 4; ++j) {
                    int gs = tn * 128 + wn * 64 + j * 16 + ml;
                    bool ok = rok && (gs < Sc);
                    float ev = __expf(acc[i][j][r] * alpha);
                    float c  = ev * ev * ri * cin[j];
                    if (!ok) c = 0.f;
                    if (ok) __builtin_nontemporal_store(c, &out[((size_t)n * Lc + gl) * Sc + gs]);
                    rmax = fmaxf(rmax, c);
                }
                rmax = fmaxf(rmax, __shfl_xor(rmax, 1));
                rmax = fmaxf(rmax, __shfl_xor(rmax, 2));
                rmax = fmaxf(rmax, __shfl_xor(rmax, 4));
                rmax = fmaxf(rmax, __shfl_xor(rmax, 8));
                if (ml == 0 && rok)
                    atomicMax(&rcm[(size_t)n * Lc + gl], __float_as_int(rmax));
            }
    }
}

// ---------------- finalize: threshold + border + mutual-NN -------------------
__global__ __launch_bounds__(256) void finalize_kernel(
    const float* __restrict__ conf, const float* __restrict__ rcm,
    const int* __restrict__ h0p, const int* __restrict__ w0p,
    const int* __restrict__ h1p, const int* __restrict__ w1p,
    float* __restrict__ out_match, float* __restrict__ out_j, float* __restrict__ out_mconf)
{
    int i = blockIdx.x * 256 + threadIdx.x;      // n*Lc + l
    if (i >= Ncst * Lc) return;
    int n = i / Lc, l = i % Lc;
    float mm = rcm[i];
    float fm = 0.f, fj = 0.f, fc = 0.f;
    if (mm > THRC) {
        int w0 = *w0p, w1 = *w1p;
        if ((l / w0) >= 2 && (l % w0) >= 2) {
            const float* rowp = conf + ((size_t)n * Lc + l) * Sc;
            for (int s = 0; s < Sc; ++s) {
                float c = rowp[s];
                if (c == mm && (s / w1) >= 2 && (s % w1) >= 2) {
                    bool ismax = true;
                    const float* colp = conf + (size_t)n * Lc * Sc + s;
                    for (int lp = 0; lp < Lc; ++lp) {
                        if (colp[(size_t)lp * Sc] > c) { ismax = false; break; }
                    }
                    if (ismax) { fm = 1.f; fj = (float)s; fc = c; break; }
                }
            }
        }
    }
    out_match[i] = fm; out_j[i] = fj; out_mconf[i] = fc;
}

extern "C" void kernel_launch(void* const* d_in, const int* in_sizes, int n_in,
                              void* d_out, int out_size, void* d_ws, size_t ws_size,
                              hipStream_t stream) {
    const float* f0 = (const float*)d_in[0];
    const float* f1 = (const float*)d_in[1];
    const int* h0p = (const int*)d_in[2];
    const int* w0p = (const int*)d_in[3];
    const int* h1p = (const int*)d_in[4];
    const int* w1p = (const int*)d_in[5];

    // workspace layout (bytes); total ~15.1 MB
    char* ws = (char*)d_ws;
    unsigned short* A2 = (unsigned short*)ws;                  // 9,961,472 B
    unsigned short* B2 = (unsigned short*)(ws + 9961472);      // 4,980,736 B
    float* rs  = (float*)(ws + 14942208);                      // 38,400 B each
    float* cs  = (float*)(ws + 14980608);
    float* rcm = (float*)(ws + 15019008);

    float* conf      = (float*)d_out;                          // [N][L][S]
    float* out_match = conf + (size_t)Ncst * Lc * Sc;
    float* out_j     = out_match + Ncst * Lc;
    float* out_mconf = out_j + Ncst * Lc;

    convert_kernel<<<(Ncst * LP * (Cc / 8) + 255) / 256, 256, 0, stream>>>(
        f0, f1, A2, B2, rs, cs, rcm);

    dim3 gg(38, 38, Ncst);   // 2888 blocks
    gemm_kernel<0><<<gg, 256, 0, stream>>>(A2, B2, nullptr, rs, cs, nullptr);
    gemm_kernel<1><<<gg, 256, 0, stream>>>(A2, B2, conf, rs, cs, (int*)rcm);

    finalize_kernel<<<(Ncst * Lc + 255) / 256, 256, 0, stream>>>(
        conf, rcm, h0p, w0p, h1p, w1p, out_match, out_j, out_mconf);
}

// Round 5
// 317.026 us; speedup vs baseline: 1.0729x; 1.0729x over previous
//
#include <hip/hip_runtime.h>

// CoarseMatching dual-softmax on MI355X — round 7.
// N=2, L=S=4800, C=256. sim = f0.f1^T/(256*0.1); conf = softmax_l * softmax_s.
// Structure (materialize-e, single GEMM):
//   convert -> gemm (shared-B f16 hi/lo, write e f32 + atomic rs/cs)
//   -> inv (csinv) -> conf (conf = e^2*(1/rs)*csinv in place, NT store, rcm)
//   -> finalize.
// Diagnosis r0-r6: total = harness fill (~115us) + gaps (~20us) + kernels.
// r6 proved shared-B GEMM ~97us/pass; r3 proved conf pass ~58us. Recompute
// (2nd GEMM pass, ~97us) is strictly worse than re-reading e (184MB, L3-warm
// since e < 256MB L3 and read immediately after write). So: one GEMM only.
// GEMM: A expanded [a_hi|a_lo] (K=512), B stored once (K=256), each B frag
// feeds 2 MFMAs. 48KB LDS (2buf x {Ahi,Alo,B} x 512 slots x 16B), 3 blocks/CU,
// double-buffered, XOR slot swizzle (0 bank conflicts, proven r3).

#define Ncst 2
#define Lc 4800
#define Sc 4800
#define Cc 256
#define KA 512          // A expanded K: [a_hi | a_lo]
#define KB 256          // B stored once: [b_hi]
#define LP 4864         // 4800 padded to 38*128
#define THRC 0.2f

typedef float f32x4 __attribute__((ext_vector_type(4)));
typedef _Float16 f16x8 __attribute__((ext_vector_type(8)));

#define AS1(p) ((__attribute__((address_space(1))) void*)(p))
#define AS3(p) ((__attribute__((address_space(3))) void*)(p))

// ---------------- conversion (+ zero accumulators) ---------------------------
// A2 [N][LP][512] = [a_hi | a_lo]; B2 [N][LP][256] = [b_hi]
__global__ __launch_bounds__(256) void convert_kernel(
    const float* __restrict__ f0, const float* __restrict__ f1,
    unsigned short* __restrict__ A2, unsigned short* __restrict__ B2,
    float* __restrict__ rs, float* __restrict__ cs)
{
    int idx = blockIdx.x * 256 + threadIdx.x;      // over N*LP*(C/8)
    if (idx < Ncst * Lc) { rs[idx] = 0.f; cs[idx] = 0.f; }   // fold init
    if (idx >= Ncst * LP * (Cc / 8)) return;
    int k8  = idx & (Cc / 8 - 1);                  // 0..31
    int row = (idx >> 5) % LP;
    int n   = idx / (LP * (Cc / 8));

    float av[8], bv[8];
    if (row < Lc) {
        const float4* pa = (const float4*)(f0 + ((size_t)n * Lc + row) * Cc + k8 * 8);
        float4 a0 = pa[0], a1 = pa[1];
        av[0]=a0.x; av[1]=a0.y; av[2]=a0.z; av[3]=a0.w;
        av[4]=a1.x; av[5]=a1.y; av[6]=a1.z; av[7]=a1.w;
        const float4* pb = (const float4*)(f1 + ((size_t)n * Sc + row) * Cc + k8 * 8);
        float4 b0 = pb[0], b1 = pb[1];
        bv[0]=b0.x; bv[1]=b0.y; bv[2]=b0.z; bv[3]=b0.w;
        bv[4]=b1.x; bv[5]=b1.y; bv[6]=b1.z; bv[7]=b1.w;
    } else {
        for (int i = 0; i < 8; ++i) { av[i] = 0.f; bv[i] = 0.f; }
    }

    _Float16 ahi[8], alo[8], bhi[8];
#pragma unroll
    for (int i = 0; i < 8; ++i) {
        _Float16 h = (_Float16)av[i];
        ahi[i] = h;
        alo[i] = (_Float16)(av[i] - (float)h);
        bhi[i] = (_Float16)bv[i];
    }
    size_t abase = ((size_t)n * LP + row) * KA + k8 * 8;
    size_t bbase = ((size_t)n * LP + row) * KB + k8 * 8;
    *(uint4*)&A2[abase]       = *(uint4*)ahi;
    *(uint4*)&A2[abase + 256] = *(uint4*)alo;
    *(uint4*)&B2[bbase]       = *(uint4*)bhi;
}

// ---------------- GEMM + fused exp + e-write + row/col sums ------------------
// 128x128 tile, 4 waves (2x2), wave-tile 64x64 = acc[4][4] via 16x16x32 f16.
// 8 b-tiles of 32 k; per tile per wave: 12 ds_read_b128 (a_hi[4],a_lo[4],b[4]),
// 32 MFMA (each b frag used twice: a_hi then a_lo).
// LDS: 2 bufs x 3 regions x 512 slots x 16B = 48 KB -> 3 blocks/CU.
// Slot swizzle: slot(row,q) = row*4 + (q ^ ((row>>1)&3)) (0 conflicts, r3).
template <int DUMMY>
__global__ __launch_bounds__(256, 3) void gemm_kernel(
    const unsigned short* __restrict__ A2, const unsigned short* __restrict__ B2,
    float* __restrict__ eout, float* __restrict__ rs, float* __restrict__ cs)
{
    __shared__ __attribute__((aligned(16))) unsigned short lds[2][1536 * 8]; // 48 KB

    // bijective XCD-aware swizzle: grid = 38*38*2 = 2888 = 8*361
    int flat = blockIdx.x + 38 * blockIdx.y + 1444 * blockIdx.z;
    int m    = (flat & 7) * 361 + (flat >> 3);
    const int tn = m % 38;
    const int tm = (m / 38) % 38;
    const int n  = m / 1444;

    const int tid  = threadIdx.x;
    const int wave = tid >> 6;
    const int lane = tid & 63;
    const int wm   = wave >> 1;     // 0..1
    const int wn   = wave & 1;      // 0..1
    const int ml   = lane & 15;
    const int kq   = lane >> 4;     // 0..3

    const unsigned short* Ab = A2 + ((size_t)n * LP + (size_t)tm * 128) * KA;
    const unsigned short* Bb = B2 + ((size_t)n * LP + (size_t)tn * 128) * KB;

    // staging: 6 chunks/thread = regions {Ahi,Alo,B} x halves {0,1}
    const unsigned short* gsrc[6];
    int gdst[6];
#pragma unroll
    for (int c = 0; c < 6; ++c) {
        int reg = c >> 1;                      // 0=Ahi 1=Alo 2=B
        int s   = (c & 1) * 256 + tid;         // slot in region
        int row = s >> 2;
        int q   = (s & 3) ^ ((row >> 1) & 3);
        if (reg == 0)      gsrc[c] = Ab + (size_t)row * KA + q * 8;
        else if (reg == 1) gsrc[c] = Ab + (size_t)row * KA + 256 + q * 8;
        else               gsrc[c] = Bb + (size_t)row * KB + q * 8;
        gdst[c] = (reg * 512 + s) * 8;
    }

    // fragment LDS element offsets (region-relative slot*8)
    int aoff[4], boff[4];
#pragma unroll
    for (int i = 0; i < 4; ++i) {
        int ar = wm * 64 + i * 16 + ml;
        aoff[i] = (ar * 4 + (kq ^ ((ar >> 1) & 3))) * 8;
        int br = wn * 64 + i * 16 + ml;
        boff[i] = (br * 4 + (kq ^ ((br >> 1) & 3))) * 8;
    }

#define STAGE(bb, tt) do { _Pragma("unroll") for (int c_ = 0; c_ < 6; ++c_) \
    __builtin_amdgcn_global_load_lds(AS1(gsrc[c_] + (tt) * 32), AS3(&lds[bb][gdst[c_]]), 16, 0, 0); } while (0)

    f32x4 acc[4][4] = {};

    STAGE(0, 0);
    __syncthreads();

#pragma unroll
    for (int t = 0; t < 8; ++t) {
        const int b = t & 1;
        if (t < 7) STAGE(b ^ 1, t + 1);
        f16x8 ah[4], al[4], bf_[4];
#pragma unroll
        for (int i = 0; i < 4; ++i) {
            ah[i]  = *(const f16x8*)&lds[b][aoff[i]];
            al[i]  = *(const f16x8*)&lds[b][4096 + aoff[i]];
            bf_[i] = *(const f16x8*)&lds[b][8192 + boff[i]];
        }
#pragma unroll
        for (int i = 0; i < 4; ++i)
#pragma unroll
            for (int j = 0; j < 4; ++j) {
                acc[i][j] = __builtin_amdgcn_mfma_f32_16x16x32_f16(ah[i], bf_[j], acc[i][j], 0, 0, 0);
                acc[i][j] = __builtin_amdgcn_mfma_f32_16x16x32_f16(al[i], bf_[j], acc[i][j], 0, 0, 0);
            }
        __syncthreads();   // tile t+1 loads landed during the 32 MFMAs
    }
#undef STAGE

    // ---- epilogue: e = exp(alpha*sim); plain store (keep L2/L3-warm for
    // conf pass); accumulate row/col sums.  D frag: col = ml, row = kq*4 + r.
    const float alpha = 5.0f / 128.0f;          // 1/(256*0.1), exact in fp32
#pragma unroll
    for (int i = 0; i < 4; ++i) {
#pragma unroll
        for (int r = 0; r < 4; ++r) {
            int gl = tm * 128 + wm * 64 + i * 16 + kq * 4 + r;
            bool rok = gl < Lc;
#pragma unroll
            for (int j = 0; j < 4; ++j) {
                int gs = tn * 128 + wn * 64 + j * 16 + ml;
                bool ok = rok && (gs < Sc);
                float ev = ok ? __expf(acc[i][j][r] * alpha) : 0.f;
                acc[i][j][r] = ev;
                if (ok) eout[((size_t)n * Lc + gl) * Sc + gs] = ev;
            }
        }
    }
    // row sums: reduce over j and ml lanes (xor 1,2,4,8 stays in quarter)
#pragma unroll
    for (int i = 0; i < 4; ++i) {
#pragma unroll
        for (int r = 0; r < 4; ++r) {
            float rp = acc[i][0][r] + acc[i][1][r] + acc[i][2][r] + acc[i][3][r];
            rp += __shfl_xor(rp, 1);
            rp += __shfl_xor(rp, 2);
            rp += __shfl_xor(rp, 4);
            rp += __shfl_xor(rp, 8);
            int gl = tm * 128 + wm * 64 + i * 16 + kq * 4 + r;
            if (ml == 0 && gl < Lc) atomicAdd(&rs[(size_t)n * Lc + gl], rp);
        }
    }
    // col sums: reduce over i,r and kq (xor 16, 32)
#pragma unroll
    for (int j = 0; j < 4; ++j) {
        float cp = 0.f;
#pragma unroll
        for (int i = 0; i < 4; ++i)
#pragma unroll
            for (int r = 0; r < 4; ++r) cp += acc[i][j][r];
        cp += __shfl_xor(cp, 16);
        cp += __shfl_xor(cp, 32);
        int gs = tn * 128 + wn * 64 + j * 16 + ml;
        if (kq == 0 && gs < Sc) atomicAdd(&cs[(size_t)n * Sc + gs], cp);
    }
}

// ---------------- reciprocal of col sums -------------------------------------
__global__ __launch_bounds__(256) void inv_kernel(
    const float* __restrict__ cs, float* __restrict__ csinv)
{
    int i = blockIdx.x * 256 + threadIdx.x;
    if (i < Ncst * Lc) csinv[i] = 1.0f / cs[i];
}

// ---------------- conf: in-place e -> conf = e^2*(1/rs)*csinv; row max -------
__global__ __launch_bounds__(256) void conf_kernel(
    float* __restrict__ confio,
    const float* __restrict__ rs, const float* __restrict__ csinv,
    float* __restrict__ rcm)
{
    __shared__ float sw[4];
    int b = blockIdx.x;                          // n*Lc + l
    int n = b / Lc;
    f32x4* row = (f32x4*)(confio + (size_t)b * Sc);
    const f32x4* civ = (const f32x4*)(csinv + (size_t)n * Sc);
    int tid = threadIdx.x;
    float riv = 1.0f / rs[b];                    // same value as r3's rsinv[b]
    float lmax = 0.f;
    for (int v = tid; v < Sc / 4; v += 256) {
        f32x4 e4 = row[v];
        f32x4 c4 = civ[v];
        f32x4 o  = e4 * e4 * riv * c4;
        __builtin_nontemporal_store(o, &row[v]);   // conf never re-read hot
        lmax = fmaxf(lmax, fmaxf(fmaxf(o.x, o.y), fmaxf(o.z, o.w)));
    }
#pragma unroll
    for (int off = 1; off < 64; off <<= 1) lmax = fmaxf(lmax, __shfl_xor(lmax, off));
    if ((tid & 63) == 0) sw[tid >> 6] = lmax;
    __syncthreads();
    if (tid == 0) rcm[b] = fmaxf(fmaxf(sw[0], sw[1]), fmaxf(sw[2], sw[3]));
}

// ---------------- finalize: threshold + border + mutual-NN -------------------
__global__ __launch_bounds__(256) void finalize_kernel(
    const float* __restrict__ conf, const float* __restrict__ rcm,
    const int* __restrict__ h0p, const int* __restrict__ w0p,
    const int* __restrict__ h1p, const int* __restrict__ w1p,
    float* __restrict__ out_match, float* __restrict__ out_j, float* __restrict__ out_mconf)
{
    int i = blockIdx.x * 256 + threadIdx.x;      // n*Lc + l
    if (i >= Ncst * Lc) return;
    int n = i / Lc, l = i % Lc;
    float mm = rcm[i];
    float fm = 0.f, fj = 0.f, fc = 0.f;
    if (mm > THRC) {
        int w0 = *w0p, w1 = *w1p;
        if ((l / w0) >= 2 && (l % w0) >= 2) {
            const float* rowp = conf + ((size_t)n * Lc + l) * Sc;
            for (int s = 0; s < Sc; ++s) {
                float c = rowp[s];
                if (c == mm && (s / w1) >= 2 && (s % w1) >= 2) {
                    bool ismax = true;
                    const float* colp = conf + (size_t)n * Lc * Sc + s;
                    for (int lp = 0; lp < Lc; ++lp) {
                        if (colp[(size_t)lp * Sc] > c) { ismax = false; break; }
                    }
                    if (ismax) { fm = 1.f; fj = (float)s; fc = c; break; }
                }
            }
        }
    }
    out_match[i] = fm; out_j[i] = fj; out_mconf[i] = fc;
}

extern "C" void kernel_launch(void* const* d_in, const int* in_sizes, int n_in,
                              void* d_out, int out_size, void* d_ws, size_t ws_size,
                              hipStream_t stream) {
    const float* f0 = (const float*)d_in[0];
    const float* f1 = (const float*)d_in[1];
    const int* h0p = (const int*)d_in[2];
    const int* w0p = (const int*)d_in[3];
    const int* h1p = (const int*)d_in[4];
    const int* w1p = (const int*)d_in[5];

    // workspace layout (bytes); total ~15.1 MB
    char* ws = (char*)d_ws;
    unsigned short* A2 = (unsigned short*)ws;                  // 9,961,472 B
    unsigned short* B2 = (unsigned short*)(ws + 9961472);      // 4,980,736 B
    float* rs    = (float*)(ws + 14942208);                    // 38,400 B each
    float* cs    = (float*)(ws + 14980608);
    float* csinv = (float*)(ws + 15019008);
    float* rcm   = (float*)(ws + 15057408);

    float* conf      = (float*)d_out;                          // [N][L][S]: e then conf
    float* out_match = conf + (size_t)Ncst * Lc * Sc;
    float* out_j     = out_match + Ncst * Lc;
    float* out_mconf = out_j + Ncst * Lc;

    convert_kernel<<<(Ncst * LP * (Cc / 8) + 255) / 256, 256, 0, stream>>>(
        f0, f1, A2, B2, rs, cs);

    dim3 gg(38, 38, Ncst);   // 2888 blocks
    gemm_kernel<0><<<gg, 256, 0, stream>>>(A2, B2, conf, rs, cs);

    inv_kernel<<<(Ncst * Lc + 255) / 256, 256, 0, stream>>>(cs, csinv);

    conf_kernel<<<Ncst * Lc, 256, 0, stream>>>(conf, rs, csinv, rcm);

    finalize_kernel<<<(Ncst * Lc + 255) / 256, 256, 0, stream>>>(
        conf, rcm, h0p, w0p, h1p, w1p, out_match, out_j, out_mconf);
}